// Round 19
// baseline (101.629 us; speedup 1.0000x reference)
//
#include <hip/hip_runtime.h>
#include <hip/hip_bf16.h>

#define NB 8
#define SEQ 2048
#define DM 1024
#define AD 64
#define NROWS (NB * SEQ)          // 16384

// exp(s/32) = 2^(s * 0.03125 * log2(e));  log2(e)/32 = 0.045084220
#define SCL2 0.04508422f

typedef __attribute__((ext_vector_type(8))) short short8;
typedef __attribute__((ext_vector_type(4))) float f32x4;

static __device__ __forceinline__ unsigned short f2bf(float f) {
    unsigned int u = __float_as_uint(f);
    u += 0x7FFFu + ((u >> 16) & 1u);
    return (unsigned short)(u >> 16);
}

static __device__ __forceinline__ f32x4 mfma16(short8 a, short8 b, f32x4 c) {
    return __builtin_amdgcn_mfma_f32_16x16x32_bf16(a, b, c, 0, 0, 0);
}

static __device__ __forceinline__ short8 pack8v(f32x4 a, f32x4 b) {
    short8 r;
    r[0] = (short)f2bf(a[0]); r[1] = (short)f2bf(a[1]);
    r[2] = (short)f2bf(a[2]); r[3] = (short)f2bf(a[3]);
    r[4] = (short)f2bf(b[0]); r[5] = (short)f2bf(b[1]);
    r[6] = (short)f2bf(b[2]); r[7] = (short)f2bf(b[3]);
    return r;
}

static __device__ __forceinline__ uint2 cvt2bf4(float4 v) {
    uint2 pk;
    pk.x = (unsigned)f2bf(v.x) | ((unsigned)f2bf(v.y) << 16);
    pk.y = (unsigned)f2bf(v.z) | ((unsigned)f2bf(v.w) << 16);
    return pk;
}

// ---------------------------------------------------------------------------
// Kernel 0: transpose + convert W (fp32 [1024][64]) -> wT bf16 [3][64][1024]
// ---------------------------------------------------------------------------
__global__ __launch_bounds__(256) void wT_kernel(
    const float* __restrict__ Wq, const float* __restrict__ Wk,
    const float* __restrict__ Wv, unsigned short* __restrict__ wT) {
    int p = blockIdx.y;
    int k0 = blockIdx.x * 64;
    const float* W = (p == 0) ? Wq : (p == 1) ? Wk : Wv;
    __shared__ unsigned short tl[64][72];
    int t = threadIdx.x;
    int c = t & 63;
    int r0 = t >> 6;
    for (int i = 0; i < 16; i++) {
        int k = r0 + i * 4;
        tl[c][k] = f2bf(W[(size_t)(k0 + k) * AD + c]);
    }
    __syncthreads();
    for (int i = 0; i < 16; i++) {
        int a = r0 + i * 4;
        wT[((size_t)p * AD + a) * DM + k0 + c] = tl[a][c];
    }
}

// ---------------------------------------------------------------------------
// Kernel 1: projection X[16384][1024] @ W[1024][64] + b -> bf16.
// r11 pipeline (twice-proven best) + BF16-IN-LDS staging: X is converted to
// bf16 in registers during the write-phase (async-split shadow), so
//  - LDS 53 -> 37 KB => 4 WG/CU = 16 waves/CU (+33% TLP),
//  - the compute phase is pure ds_read_b128 -> MFMA (no f2bf/pack),
//  - LDS traffic on the X path halves.
// Numerically bit-identical (same f2bf on the same values, moved earlier).
// grid (256, 3), block 256 (wave w owns rows w*16..w*16+15 of 64-row tile).
// ---------------------------------------------------------------------------
__global__ __launch_bounds__(256, 4) void proj_kernel(
    const float* __restrict__ q_in, const float* __restrict__ k_in,
    const float* __restrict__ v_in, const float* __restrict__ bq,
    const float* __restrict__ bk, const float* __restrict__ bv,
    const unsigned short* __restrict__ wT,
    unsigned short* __restrict__ q_out, unsigned short* __restrict__ k_out,
    unsigned short* __restrict__ vT_out) {
    int p = blockIdx.y;
    int rbase = blockIdx.x * 64;
    const float* X = (p == 0) ? q_in : (p == 1) ? k_in : v_in;
    const float* bias = (p == 0) ? bq : (p == 1) ? bk : bv;
    const unsigned short* wTp = wT + (size_t)p * AD * DM;

    __shared__ unsigned short xsb[2][64][72];  // bf16 X chunk, 144B row stride
    __shared__ unsigned short wsm[2][64][72];  // bf16 W chunk

    int t = threadIdx.x;
    int lane = t & 63;
    int w = t >> 6;
    int arow = lane & 15;
    int agrp = lane >> 4;

    int srow = t >> 4;        // 0..15
    int scol = (t & 15) * 4;  // element col (fp32 in, bf16 out)
    int wrow = t >> 2;        // 0..63
    int wcol = (t & 3) * 16;  // bf16 col

    const float* Xb = X + (size_t)rbase * DM;

    f32x4 acc[4];
#pragma unroll
    for (int ct = 0; ct < 4; ct++) acc[ct] = (f32x4){0.f, 0.f, 0.f, 0.f};

    float4 px0, px1, px2, px3;
    float4 pw0, pw1;

    // prologue: load + convert + write chunk 0
    px0 = *reinterpret_cast<const float4*>(&Xb[(size_t)(0 * 16 + srow) * DM + scol]);
    px1 = *reinterpret_cast<const float4*>(&Xb[(size_t)(1 * 16 + srow) * DM + scol]);
    px2 = *reinterpret_cast<const float4*>(&Xb[(size_t)(2 * 16 + srow) * DM + scol]);
    px3 = *reinterpret_cast<const float4*>(&Xb[(size_t)(3 * 16 + srow) * DM + scol]);
    {
        const char* wp = reinterpret_cast<const char*>(wTp + (size_t)wrow * DM + wcol);
        pw0 = *reinterpret_cast<const float4*>(wp);
        pw1 = *reinterpret_cast<const float4*>(wp + 16);
    }
    *reinterpret_cast<uint2*>(&xsb[0][0 * 16 + srow][scol]) = cvt2bf4(px0);
    *reinterpret_cast<uint2*>(&xsb[0][1 * 16 + srow][scol]) = cvt2bf4(px1);
    *reinterpret_cast<uint2*>(&xsb[0][2 * 16 + srow][scol]) = cvt2bf4(px2);
    *reinterpret_cast<uint2*>(&xsb[0][3 * 16 + srow][scol]) = cvt2bf4(px3);
    *reinterpret_cast<float4*>(&wsm[0][wrow][wcol]) = pw0;
    *reinterpret_cast<float4*>(&wsm[0][wrow][wcol + 8]) = pw1;
    __syncthreads();

    for (int c = 0; c < 16; ++c) {
        int bu = c & 1;
        if (c < 15) {
            int kb = (c + 1) * 64;
            px0 = *reinterpret_cast<const float4*>(&Xb[(size_t)(0 * 16 + srow) * DM + kb + scol]);
            px1 = *reinterpret_cast<const float4*>(&Xb[(size_t)(1 * 16 + srow) * DM + kb + scol]);
            px2 = *reinterpret_cast<const float4*>(&Xb[(size_t)(2 * 16 + srow) * DM + kb + scol]);
            px3 = *reinterpret_cast<const float4*>(&Xb[(size_t)(3 * 16 + srow) * DM + kb + scol]);
            const char* wp = reinterpret_cast<const char*>(wTp + (size_t)wrow * DM + kb + wcol);
            pw0 = *reinterpret_cast<const float4*>(wp);
            pw1 = *reinterpret_cast<const float4*>(wp + 16);
        }
        // ---- compute chunk c: pure ds_read_b128 -> MFMA ----
        const unsigned short* xr = &xsb[bu][w * 16 + arow][0];
#pragma unroll
        for (int s = 0; s < 2; ++s) {
            short8 af = *reinterpret_cast<const short8*>(&xr[s * 32 + agrp * 8]);
#pragma unroll
            for (int ct = 0; ct < 4; ++ct) {
                short8 bf = *reinterpret_cast<const short8*>(
                    &wsm[bu][ct * 16 + arow][s * 32 + agrp * 8]);
                acc[ct] = mfma16(af, bf, acc[ct]);
            }
        }
        // ---- convert + write prefetched chunk c+1 (vmcnt wait lands here) ----
        if (c < 15) {
            int bo = bu ^ 1;
            *reinterpret_cast<uint2*>(&xsb[bo][0 * 16 + srow][scol]) = cvt2bf4(px0);
            *reinterpret_cast<uint2*>(&xsb[bo][1 * 16 + srow][scol]) = cvt2bf4(px1);
            *reinterpret_cast<uint2*>(&xsb[bo][2 * 16 + srow][scol]) = cvt2bf4(px2);
            *reinterpret_cast<uint2*>(&xsb[bo][3 * 16 + srow][scol]) = cvt2bf4(px3);
            *reinterpret_cast<float4*>(&wsm[bo][wrow][wcol]) = pw0;
            *reinterpret_cast<float4*>(&wsm[bo][wrow][wcol + 8]) = pw1;
        }
        __syncthreads();
    }

    if (p < 2) {
        unsigned short* outp = (p == 0) ? q_out : k_out;
#pragma unroll
        for (int ct = 0; ct < 4; ct++) {
            int a = ct * 16 + arow;
            float bv_ = bias[a];
#pragma unroll
            for (int rr = 0; rr < 4; rr++) {
                int row = rbase + w * 16 + agrp * 4 + rr;
                outp[(size_t)row * AD + a] = f2bf(acc[ct][rr] + bv_);
            }
        }
    } else {
        // transpose via LDS scratch (reuse xsb), then write vT[b][a][s]
        unsigned short* sc = (unsigned short*)&xsb[0][0][0];  // [64][72]
#pragma unroll
        for (int ct = 0; ct < 4; ct++) {
            int a = ct * 16 + arow;
            float bv_ = bias[a];
#pragma unroll
            for (int rr = 0; rr < 4; rr++) {
                int row = w * 16 + agrp * 4 + rr;
                sc[a * 72 + row] = f2bf(acc[ct][rr] + bv_);
            }
        }
        __syncthreads();
        int bidx = rbase >> 11;
        int sbase = rbase & 2047;
        int rr = t & 63;
        for (int i = 0; i < 16; i++) {
            int a = (t >> 6) + i * 4;
            vT_out[((size_t)bidx * AD + a) * SEQ + sbase + rr] = sc[a * 72 + rr];
        }
    }
}

// ---------------------------------------------------------------------------
// Kernel 2 (FULLY FUSED attention): Phase A computes the softmax denominator
// in-block (wave w sums exp over its 256 keys with Q-frags already in regs;
// 8 wave-partials reduce through 1 KB LDS; lanes 0-31 compute lr = -log2(S)),
// then Phase B normalizes, writes attn (coalesced, nontemporal), PV-MFMAs,
// and reduces ctx across the 8 waves. grid 512 = (qt 64, b 8), b in low 3
// bits (XCD pin). block 512. LDS ~71 KB -> 2 WG/CU (16 waves/CU).
// ---------------------------------------------------------------------------
__global__ __launch_bounds__(512, 2) void attn2_kernel(
    const unsigned short* __restrict__ qb, const unsigned short* __restrict__ kb,
    const unsigned short* __restrict__ vT, float* __restrict__ attn_out,
    float* __restrict__ ctx_out) {
    int blk = blockIdx.x;
    int b = blk & 7;
    int qbase = (blk >> 3) * 32;

    __shared__ float sf[8][32][68];
    __shared__ float wsum[8][32];
    __shared__ float lr_lds[32];

    int t = threadIdx.x;
    int lane = t & 63;
    int w = t >> 6;       // 0..7
    int arow = lane & 15;
    int agrp = lane >> 4;

    const unsigned short* qrow = qb + ((size_t)b * SEQ + qbase) * AD;
    short8 qf0a = *reinterpret_cast<const short8*>(qrow + (size_t)arow * AD + agrp * 8);
    short8 qf1a = *reinterpret_cast<const short8*>(qrow + (size_t)arow * AD + 32 + agrp * 8);
    short8 qf0b = *reinterpret_cast<const short8*>(qrow + (size_t)(16 + arow) * AD + agrp * 8);
    short8 qf1b = *reinterpret_cast<const short8*>(qrow + (size_t)(16 + arow) * AD + 32 + agrp * 8);
    const unsigned short* kbp = kb + (size_t)b * SEQ * AD;
    const unsigned short* vTb = vT + (size_t)b * AD * SEQ;
    float* attn_b = attn_out + ((size_t)b * SEQ + qbase) * SEQ;

    int keybase = w * 256;

    // ---- Phase A: per-wave exp-sums over its 256 keys, 8-wave reduce -> lr
    float sA[4] = {0.f, 0.f, 0.f, 0.f};
    float sB[4] = {0.f, 0.f, 0.f, 0.f};
    for (int kt = 0; kt < 16; ++kt) {
        int key0 = keybase + kt * 16;
        const unsigned short* krow = kbp + (size_t)(key0 + arow) * AD;
        short8 kf0 = *reinterpret_cast<const short8*>(krow + agrp * 8);
        short8 kf1 = *reinterpret_cast<const short8*>(krow + 32 + agrp * 8);
        f32x4 aA = (f32x4){0.f, 0.f, 0.f, 0.f};
        aA = mfma16(qf0a, kf0, aA);
        aA = mfma16(qf1a, kf1, aA);
        f32x4 aB = (f32x4){0.f, 0.f, 0.f, 0.f};
        aB = mfma16(qf0b, kf0, aB);
        aB = mfma16(qf1b, kf1, aB);
#pragma unroll
        for (int r = 0; r < 4; r++) {
            sA[r] += __builtin_amdgcn_exp2f(aA[r] * SCL2);
            sB[r] += __builtin_amdgcn_exp2f(aB[r] * SCL2);
        }
    }
#pragma unroll
    for (int r = 0; r < 4; r++) {
#pragma unroll
        for (int off = 1; off < 16; off <<= 1) {
            sA[r] += __shfl_xor(sA[r], off);
            sB[r] += __shfl_xor(sB[r], off);
        }
    }
    if (arow == 0) {
#pragma unroll
        for (int r = 0; r < 4; r++) {
            wsum[w][agrp * 4 + r] = sA[r];
            wsum[w][16 + agrp * 4 + r] = sB[r];
        }
    }
    __syncthreads();
    if (t < 32) {
        float S = ((wsum[0][t] + wsum[1][t]) + (wsum[2][t] + wsum[3][t])) +
                  ((wsum[4][t] + wsum[5][t]) + (wsum[6][t] + wsum[7][t]));
        lr_lds[t] = -__builtin_amdgcn_logf(S);  // amdgcn logf IS log2
    }
    __syncthreads();

    float lrA[4], lrB[4];
#pragma unroll
    for (int r = 0; r < 4; r++) {
        lrA[r] = lr_lds[agrp * 4 + r];
        lrB[r] = lr_lds[16 + agrp * 4 + r];
    }

    // ---- Phase B: recompute QK^T, normalize, write attn, PV ----
    f32x4 caccA[4], caccB[4];
#pragma unroll
    for (int ct = 0; ct < 4; ct++) {
        caccA[ct] = (f32x4){0.f, 0.f, 0.f, 0.f};
        caccB[ct] = (f32x4){0.f, 0.f, 0.f, 0.f};
    }

    for (int g = 0; g < 4; ++g) {
        int key0b = keybase + g * 64;
#pragma unroll
        for (int kb4 = 0; kb4 < 4; ++kb4) {
            int k0 = key0b + kb4 * 16;
            const unsigned short* krow = kbp + (size_t)(k0 + arow) * AD;
            short8 kf0 = *reinterpret_cast<const short8*>(krow + agrp * 8);
            short8 kf1 = *reinterpret_cast<const short8*>(krow + 32 + agrp * 8);
            f32x4 aA = (f32x4){0.f, 0.f, 0.f, 0.f};
            aA = mfma16(qf0a, kf0, aA);
            aA = mfma16(qf1a, kf1, aA);
            f32x4 aB = (f32x4){0.f, 0.f, 0.f, 0.f};
            aB = mfma16(qf0b, kf0, aB);
            aB = mfma16(qf1b, kf1, aB);
#pragma unroll
            for (int r = 0; r < 4; r++) {
                sf[w][agrp * 4 + r][kb4 * 16 + arow] =
                    __builtin_amdgcn_exp2f(aA[r] * SCL2 + lrA[r]);
                sf[w][16 + agrp * 4 + r][kb4 * 16 + arow] =
                    __builtin_amdgcn_exp2f(aB[r] * SCL2 + lrB[r]);
            }
        }
        // coalesced attn stores: 32 rows x 64 keys, 16 B/lane per store
#pragma unroll
        for (int j = 0; j < 8; ++j) {
            int row = j * 4 + agrp;
            int c4 = arow * 4;
            f32x4 vv = *reinterpret_cast<const f32x4*>(&sf[w][row][c4]);
            __builtin_nontemporal_store(
                vv, reinterpret_cast<f32x4*>(&attn_b[(size_t)row * SEQ + key0b + c4]));
        }
        // PV: A-frags from sf (both q-groups), V-frag loaded once, used twice
#pragma unroll
        for (int ks = 0; ks < 2; ++ks) {
            f32x4 pa0 = *reinterpret_cast<const f32x4*>(&sf[w][arow][ks * 32 + agrp * 8]);
            f32x4 pa1 = *reinterpret_cast<const f32x4*>(&sf[w][arow][ks * 32 + agrp * 8 + 4]);
            short8 pfA = pack8v(pa0, pa1);
            f32x4 pb0 = *reinterpret_cast<const f32x4*>(&sf[w][16 + arow][ks * 32 + agrp * 8]);
            f32x4 pb1 = *reinterpret_cast<const f32x4*>(&sf[w][16 + arow][ks * 32 + agrp * 8 + 4]);
            short8 pfB = pack8v(pb0, pb1);
#pragma unroll
            for (int ct = 0; ct < 4; ct++) {
                const unsigned short* vr =
                    vTb + (size_t)(ct * 16 + arow) * SEQ + key0b + ks * 32 + agrp * 8;
                short8 vv = *reinterpret_cast<const short8*>(vr);
                caccA[ct] = mfma16(pfA, vv, caccA[ct]);
                caccB[ct] = mfma16(pfB, vv, caccB[ct]);
            }
        }
    }

    // ---- 8-wave ctx reduce via LDS, then direct ctx write ----
    __syncthreads();  // all waves done with their sf score slices
#pragma unroll
    for (int ct = 0; ct < 4; ct++)
#pragma unroll
        for (int r = 0; r < 4; r++) {
            sf[w][agrp * 4 + r][ct * 16 + arow] = caccA[ct][r];
            sf[w][16 + agrp * 4 + r][ct * 16 + arow] = caccB[ct][r];
        }
    __syncthreads();

    float* ctx_b = ctx_out + ((size_t)b * SEQ + qbase) * AD;
    for (int i = t; i < 32 * 64; i += 512) {
        int r = i >> 6, a = i & 63;
        float v = ((sf[0][r][a] + sf[1][r][a]) + (sf[2][r][a] + sf[3][r][a])) +
                  ((sf[4][r][a] + sf[5][r][a]) + (sf[6][r][a] + sf[7][r][a]));
        __builtin_nontemporal_store(v, &ctx_b[(size_t)r * AD + a]);
    }
}

// ---------------------------------------------------------------------------
extern "C" void kernel_launch(void* const* d_in, const int* in_sizes, int n_in,
                              void* d_out, int out_size, void* d_ws, size_t ws_size,
                              hipStream_t stream) {
    const float* q_in = (const float*)d_in[0];
    const float* k_in = (const float*)d_in[1];
    const float* v_in = (const float*)d_in[2];
    const float* Wq = (const float*)d_in[3];
    const float* bq = (const float*)d_in[4];
    const float* Wk = (const float*)d_in[5];
    const float* bk = (const float*)d_in[6];
    const float* Wv = (const float*)d_in[7];
    const float* bv = (const float*)d_in[8];

    char* ws = (char*)d_ws;
    unsigned short* q_bf = (unsigned short*)(ws);                    // 2 MB
    unsigned short* k_bf = (unsigned short*)(ws + (2u << 20));       // 2 MB
    unsigned short* vT   = (unsigned short*)(ws + (4u << 20));       // 2 MB
    unsigned short* wT   = (unsigned short*)(ws + (6u << 20));       // 384 KB

    float* ctx_out = (float*)d_out;
    float* attn_out = ctx_out + (size_t)NB * SEQ * AD;

    hipLaunchKernelGGL(wT_kernel, dim3(16, 3), dim3(256), 0, stream, Wq, Wk, Wv, wT);
    hipLaunchKernelGGL(proj_kernel, dim3(256, 3), dim3(256), 0, stream,
                       q_in, k_in, v_in, bq, bk, bv, wT, q_bf, k_bf, vT);
    hipLaunchKernelGGL(attn2_kernel, dim3(512), dim3(512), 0, stream,
                       q_bf, k_bf, vT, attn_out, ctx_out);
}

// Round 20
// 100.472 us; speedup vs baseline: 1.0115x; 1.0115x over previous
//
#include <hip/hip_runtime.h>
#include <hip/hip_bf16.h>

#define NB 8
#define SEQ 2048
#define DM 1024
#define AD 64
#define NROWS (NB * SEQ)          // 16384

// exp(s/32) = 2^(s * 0.03125 * log2(e));  log2(e)/32 = 0.045084220
#define SCL2 0.04508422f

typedef __attribute__((ext_vector_type(8))) short short8;
typedef __attribute__((ext_vector_type(4))) float f32x4;

static __device__ __forceinline__ unsigned short f2bf(float f) {
    unsigned int u = __float_as_uint(f);
    u += 0x7FFFu + ((u >> 16) & 1u);
    return (unsigned short)(u >> 16);
}

static __device__ __forceinline__ f32x4 mfma16(short8 a, short8 b, f32x4 c) {
    return __builtin_amdgcn_mfma_f32_16x16x32_bf16(a, b, c, 0, 0, 0);
}

static __device__ __forceinline__ short8 pack8v(f32x4 a, f32x4 b) {
    short8 r;
    r[0] = (short)f2bf(a[0]); r[1] = (short)f2bf(a[1]);
    r[2] = (short)f2bf(a[2]); r[3] = (short)f2bf(a[3]);
    r[4] = (short)f2bf(b[0]); r[5] = (short)f2bf(b[1]);
    r[6] = (short)f2bf(b[2]); r[7] = (short)f2bf(b[3]);
    return r;
}

static __device__ __forceinline__ uint2 cvt2bf4(float4 v) {
    uint2 pk;
    pk.x = (unsigned)f2bf(v.x) | ((unsigned)f2bf(v.y) << 16);
    pk.y = (unsigned)f2bf(v.z) | ((unsigned)f2bf(v.w) << 16);
    return pk;
}

// ---------------------------------------------------------------------------
// Kernel 0: transpose + convert W (fp32 [1024][64]) -> wT bf16 [3][64][1024]
// ---------------------------------------------------------------------------
__global__ __launch_bounds__(256) void wT_kernel(
    const float* __restrict__ Wq, const float* __restrict__ Wk,
    const float* __restrict__ Wv, unsigned short* __restrict__ wT) {
    int p = blockIdx.y;
    int k0 = blockIdx.x * 64;
    const float* W = (p == 0) ? Wq : (p == 1) ? Wk : Wv;
    __shared__ unsigned short tl[64][72];
    int t = threadIdx.x;
    int c = t & 63;
    int r0 = t >> 6;
    for (int i = 0; i < 16; i++) {
        int k = r0 + i * 4;
        tl[c][k] = f2bf(W[(size_t)(k0 + k) * AD + c]);
    }
    __syncthreads();
    for (int i = 0; i < 16; i++) {
        int a = r0 + i * 4;
        wT[((size_t)p * AD + a) * DM + k0 + c] = tl[a][c];
    }
}

// ---------------------------------------------------------------------------
// Kernel 1: projection X[16384][1024] @ W[1024][64] + b -> bf16.
// r11/r19 pipeline + DEPTH-2 via two named register sets (A/B) in a manually
// 2x-unrolled loop: at iteration c the wave issues loads for chunk c+3 into
// the set just freed, while the set written this iteration was loaded a FULL
// iteration earlier (>= latency -> wait ~0), and the younger set's 6 loads
// stay outstanding ACROSS the barrier. r11's depth-1 waited ~600cy/iter
// (load->use distance = one compute phase only) => the 2.4 TB/s plateau.
// bf16-in-LDS staging (r19): compute phase is pure ds_read_b128 -> MFMA.
// grid (256, 3), block 256 (wave w owns rows w*16..w*16+15 of 64-row tile).
// ---------------------------------------------------------------------------
__global__ __launch_bounds__(256, 2) void proj_kernel(
    const float* __restrict__ q_in, const float* __restrict__ k_in,
    const float* __restrict__ v_in, const float* __restrict__ bq,
    const float* __restrict__ bk, const float* __restrict__ bv,
    const unsigned short* __restrict__ wT,
    unsigned short* __restrict__ q_out, unsigned short* __restrict__ k_out,
    unsigned short* __restrict__ vT_out) {
    int p = blockIdx.y;
    int rbase = blockIdx.x * 64;
    const float* X = (p == 0) ? q_in : (p == 1) ? k_in : v_in;
    const float* bias = (p == 0) ? bq : (p == 1) ? bk : bv;
    const unsigned short* wTp = wT + (size_t)p * AD * DM;

    __shared__ unsigned short xsb[2][64][72];  // bf16 X chunk
    __shared__ unsigned short wsm[2][64][72];  // bf16 W chunk

    int t = threadIdx.x;
    int lane = t & 63;
    int w = t >> 6;
    int arow = lane & 15;
    int agrp = lane >> 4;

    int srow = t >> 4;        // 0..15
    int scol = (t & 15) * 4;  // element col
    int wrow = t >> 2;        // 0..63
    int wcol = (t & 3) * 16;  // bf16 col

    const float* Xb = X + (size_t)rbase * DM;

    f32x4 acc[4];
#pragma unroll
    for (int ct = 0; ct < 4; ct++) acc[ct] = (f32x4){0.f, 0.f, 0.f, 0.f};

    // register sets A and B (named -> both stay live; rule: static indexing)
    float4 xa0, xa1, xa2, xa3, wa0, wa1;
    float4 xb0, xb1, xb2, xb3, wb0, wb1;

#define LOADSET(s0, s1, s2, s3, sw0, sw1, kb)                                   \
    {                                                                           \
        s0 = *reinterpret_cast<const float4*>(&Xb[(size_t)(0 * 16 + srow) * DM + (kb) + scol]); \
        s1 = *reinterpret_cast<const float4*>(&Xb[(size_t)(1 * 16 + srow) * DM + (kb) + scol]); \
        s2 = *reinterpret_cast<const float4*>(&Xb[(size_t)(2 * 16 + srow) * DM + (kb) + scol]); \
        s3 = *reinterpret_cast<const float4*>(&Xb[(size_t)(3 * 16 + srow) * DM + (kb) + scol]); \
        const char* wp_ = reinterpret_cast<const char*>(wTp + (size_t)wrow * DM + (kb) + wcol); \
        sw0 = *reinterpret_cast<const float4*>(wp_);                            \
        sw1 = *reinterpret_cast<const float4*>(wp_ + 16);                       \
    }

#define WRITESET(s0, s1, s2, s3, sw0, sw1, bo)                                  \
    {                                                                           \
        *reinterpret_cast<uint2*>(&xsb[bo][0 * 16 + srow][scol]) = cvt2bf4(s0); \
        *reinterpret_cast<uint2*>(&xsb[bo][1 * 16 + srow][scol]) = cvt2bf4(s1); \
        *reinterpret_cast<uint2*>(&xsb[bo][2 * 16 + srow][scol]) = cvt2bf4(s2); \
        *reinterpret_cast<uint2*>(&xsb[bo][3 * 16 + srow][scol]) = cvt2bf4(s3); \
        *reinterpret_cast<float4*>(&wsm[bo][wrow][wcol]) = sw0;                 \
        *reinterpret_cast<float4*>(&wsm[bo][wrow][wcol + 8]) = sw1;             \
    }

#define COMPUTE(bu)                                                             \
    {                                                                           \
        const unsigned short* xr_ = &xsb[bu][w * 16 + arow][0];                 \
        _Pragma("unroll") for (int s = 0; s < 2; ++s) {                         \
            short8 af = *reinterpret_cast<const short8*>(&xr_[s * 32 + agrp * 8]); \
            _Pragma("unroll") for (int ct = 0; ct < 4; ++ct) {                  \
                short8 bf = *reinterpret_cast<const short8*>(                   \
                    &wsm[bu][ct * 16 + arow][s * 32 + agrp * 8]);               \
                acc[ct] = mfma16(af, bf, acc[ct]);                              \
            }                                                                   \
        }                                                                       \
    }

    // prologue: chunk0 -> LDS buf0; A <- chunk1; B <- chunk2 (both in flight)
    LOADSET(xa0, xa1, xa2, xa3, wa0, wa1, 0);
    WRITESET(xa0, xa1, xa2, xa3, wa0, wa1, 0);
    LOADSET(xa0, xa1, xa2, xa3, wa0, wa1, 64);
    LOADSET(xb0, xb1, xb2, xb3, wb0, wb1, 128);
    __syncthreads();

#pragma unroll
    for (int cp = 0; cp < 8; ++cp) {
        int c0 = 2 * cp;      // even iteration
        // buf[0] has chunk c0; A holds chunk c0+1 (loaded a full iter ago)
        COMPUTE(0);
        if (c0 + 1 < 16) WRITESET(xa0, xa1, xa2, xa3, wa0, wa1, 1);
        if (c0 + 3 < 16) LOADSET(xa0, xa1, xa2, xa3, wa0, wa1, (c0 + 3) * 64);
        __syncthreads();
        // odd iteration c0+1: buf[1] has chunk c0+1; B holds chunk c0+2
        COMPUTE(1);
        if (c0 + 2 < 16) WRITESET(xb0, xb1, xb2, xb3, wb0, wb1, 0);
        if (c0 + 4 < 16) LOADSET(xb0, xb1, xb2, xb3, wb0, wb1, (c0 + 4) * 64);
        __syncthreads();
    }
#undef LOADSET
#undef WRITESET
#undef COMPUTE

    if (p < 2) {
        unsigned short* outp = (p == 0) ? q_out : k_out;
#pragma unroll
        for (int ct = 0; ct < 4; ct++) {
            int a = ct * 16 + arow;
            float bv_ = bias[a];
#pragma unroll
            for (int rr = 0; rr < 4; rr++) {
                int row = rbase + w * 16 + agrp * 4 + rr;
                outp[(size_t)row * AD + a] = f2bf(acc[ct][rr] + bv_);
            }
        }
    } else {
        // transpose via LDS scratch (reuse xsb), then write vT[b][a][s]
        unsigned short* sc = (unsigned short*)&xsb[0][0][0];  // [64][72]
#pragma unroll
        for (int ct = 0; ct < 4; ct++) {
            int a = ct * 16 + arow;
            float bv_ = bias[a];
#pragma unroll
            for (int rr = 0; rr < 4; rr++) {
                int row = w * 16 + agrp * 4 + rr;
                sc[a * 72 + row] = f2bf(acc[ct][rr] + bv_);
            }
        }
        __syncthreads();
        int bidx = rbase >> 11;
        int sbase = rbase & 2047;
        int rr = t & 63;
        for (int i = 0; i < 16; i++) {
            int a = (t >> 6) + i * 4;
            vT_out[((size_t)bidx * AD + a) * SEQ + sbase + rr] = sc[a * 72 + rr];
        }
    }
}

// ---------------------------------------------------------------------------
// Kernel 2 (FULLY FUSED attention): Phase A computes the softmax denominator
// in-block, Phase B normalizes, writes attn (coalesced, nontemporal),
// PV-MFMAs, and reduces ctx across the 8 waves. grid 512 = (qt 64, b 8),
// b in low 3 bits (XCD pin). block 512. LDS ~71 KB -> 2 WG/CU.
// ---------------------------------------------------------------------------
__global__ __launch_bounds__(512, 2) void attn2_kernel(
    const unsigned short* __restrict__ qb, const unsigned short* __restrict__ kb,
    const unsigned short* __restrict__ vT, float* __restrict__ attn_out,
    float* __restrict__ ctx_out) {
    int blk = blockIdx.x;
    int b = blk & 7;
    int qbase = (blk >> 3) * 32;

    __shared__ float sf[8][32][68];
    __shared__ float wsum[8][32];
    __shared__ float lr_lds[32];

    int t = threadIdx.x;
    int lane = t & 63;
    int w = t >> 6;       // 0..7
    int arow = lane & 15;
    int agrp = lane >> 4;

    const unsigned short* qrow = qb + ((size_t)b * SEQ + qbase) * AD;
    short8 qf0a = *reinterpret_cast<const short8*>(qrow + (size_t)arow * AD + agrp * 8);
    short8 qf1a = *reinterpret_cast<const short8*>(qrow + (size_t)arow * AD + 32 + agrp * 8);
    short8 qf0b = *reinterpret_cast<const short8*>(qrow + (size_t)(16 + arow) * AD + agrp * 8);
    short8 qf1b = *reinterpret_cast<const short8*>(qrow + (size_t)(16 + arow) * AD + 32 + agrp * 8);
    const unsigned short* kbp = kb + (size_t)b * SEQ * AD;
    const unsigned short* vTb = vT + (size_t)b * AD * SEQ;
    float* attn_b = attn_out + ((size_t)b * SEQ + qbase) * SEQ;

    int keybase = w * 256;

    // ---- Phase A: per-wave exp-sums over its 256 keys, 8-wave reduce -> lr
    float sA[4] = {0.f, 0.f, 0.f, 0.f};
    float sB[4] = {0.f, 0.f, 0.f, 0.f};
    for (int kt = 0; kt < 16; ++kt) {
        int key0 = keybase + kt * 16;
        const unsigned short* krow = kbp + (size_t)(key0 + arow) * AD;
        short8 kf0 = *reinterpret_cast<const short8*>(krow + agrp * 8);
        short8 kf1 = *reinterpret_cast<const short8*>(krow + 32 + agrp * 8);
        f32x4 aA = (f32x4){0.f, 0.f, 0.f, 0.f};
        aA = mfma16(qf0a, kf0, aA);
        aA = mfma16(qf1a, kf1, aA);
        f32x4 aB = (f32x4){0.f, 0.f, 0.f, 0.f};
        aB = mfma16(qf0b, kf0, aB);
        aB = mfma16(qf1b, kf1, aB);
#pragma unroll
        for (int r = 0; r < 4; r++) {
            sA[r] += __builtin_amdgcn_exp2f(aA[r] * SCL2);
            sB[r] += __builtin_amdgcn_exp2f(aB[r] * SCL2);
        }
    }
#pragma unroll
    for (int r = 0; r < 4; r++) {
#pragma unroll
        for (int off = 1; off < 16; off <<= 1) {
            sA[r] += __shfl_xor(sA[r], off);
            sB[r] += __shfl_xor(sB[r], off);
        }
    }
    if (arow == 0) {
#pragma unroll
        for (int r = 0; r < 4; r++) {
            wsum[w][agrp * 4 + r] = sA[r];
            wsum[w][16 + agrp * 4 + r] = sB[r];
        }
    }
    __syncthreads();
    if (t < 32) {
        float S = ((wsum[0][t] + wsum[1][t]) + (wsum[2][t] + wsum[3][t])) +
                  ((wsum[4][t] + wsum[5][t]) + (wsum[6][t] + wsum[7][t]));
        lr_lds[t] = -__builtin_amdgcn_logf(S);  // amdgcn logf IS log2
    }
    __syncthreads();

    float lrA[4], lrB[4];
#pragma unroll
    for (int r = 0; r < 4; r++) {
        lrA[r] = lr_lds[agrp * 4 + r];
        lrB[r] = lr_lds[16 + agrp * 4 + r];
    }

    // ---- Phase B: recompute QK^T, normalize, write attn, PV ----
    f32x4 caccA[4], caccB[4];
#pragma unroll
    for (int ct = 0; ct < 4; ct++) {
        caccA[ct] = (f32x4){0.f, 0.f, 0.f, 0.f};
        caccB[ct] = (f32x4){0.f, 0.f, 0.f, 0.f};
    }

    for (int g = 0; g < 4; ++g) {
        int key0b = keybase + g * 64;
#pragma unroll
        for (int kb4 = 0; kb4 < 4; ++kb4) {
            int k0 = key0b + kb4 * 16;
            const unsigned short* krow = kbp + (size_t)(k0 + arow) * AD;
            short8 kf0 = *reinterpret_cast<const short8*>(krow + agrp * 8);
            short8 kf1 = *reinterpret_cast<const short8*>(krow + 32 + agrp * 8);
            f32x4 aA = (f32x4){0.f, 0.f, 0.f, 0.f};
            aA = mfma16(qf0a, kf0, aA);
            aA = mfma16(qf1a, kf1, aA);
            f32x4 aB = (f32x4){0.f, 0.f, 0.f, 0.f};
            aB = mfma16(qf0b, kf0, aB);
            aB = mfma16(qf1b, kf1, aB);
#pragma unroll
            for (int r = 0; r < 4; r++) {
                sf[w][agrp * 4 + r][kb4 * 16 + arow] =
                    __builtin_amdgcn_exp2f(aA[r] * SCL2 + lrA[r]);
                sf[w][16 + agrp * 4 + r][kb4 * 16 + arow] =
                    __builtin_amdgcn_exp2f(aB[r] * SCL2 + lrB[r]);
            }
        }
        // coalesced attn stores: 32 rows x 64 keys, 16 B/lane per store
#pragma unroll
        for (int j = 0; j < 8; ++j) {
            int row = j * 4 + agrp;
            int c4 = arow * 4;
            f32x4 vv = *reinterpret_cast<const f32x4*>(&sf[w][row][c4]);
            __builtin_nontemporal_store(
                vv, reinterpret_cast<f32x4*>(&attn_b[(size_t)row * SEQ + key0b + c4]));
        }
        // PV: A-frags from sf (both q-groups), V-frag loaded once, used twice
#pragma unroll
        for (int ks = 0; ks < 2; ++ks) {
            f32x4 pa0 = *reinterpret_cast<const f32x4*>(&sf[w][arow][ks * 32 + agrp * 8]);
            f32x4 pa1 = *reinterpret_cast<const f32x4*>(&sf[w][arow][ks * 32 + agrp * 8 + 4]);
            short8 pfA = pack8v(pa0, pa1);
            f32x4 pb0 = *reinterpret_cast<const f32x4*>(&sf[w][16 + arow][ks * 32 + agrp * 8]);
            f32x4 pb1 = *reinterpret_cast<const f32x4*>(&sf[w][16 + arow][ks * 32 + agrp * 8 + 4]);
            short8 pfB = pack8v(pb0, pb1);
#pragma unroll
            for (int ct = 0; ct < 4; ct++) {
                const unsigned short* vr =
                    vTb + (size_t)(ct * 16 + arow) * SEQ + key0b + ks * 32 + agrp * 8;
                short8 vv = *reinterpret_cast<const short8*>(vr);
                caccA[ct] = mfma16(pfA, vv, caccA[ct]);
                caccB[ct] = mfma16(pfB, vv, caccB[ct]);
            }
        }
    }

    // ---- 8-wave ctx reduce via LDS, then direct ctx write ----
    __syncthreads();  // all waves done with their sf score slices
#pragma unroll
    for (int ct = 0; ct < 4; ct++)
#pragma unroll
        for (int r = 0; r < 4; r++) {
            sf[w][agrp * 4 + r][ct * 16 + arow] = caccA[ct][r];
            sf[w][16 + agrp * 4 + r][ct * 16 + arow] = caccB[ct][r];
        }
    __syncthreads();

    float* ctx_b = ctx_out + ((size_t)b * SEQ + qbase) * AD;
    for (int i = t; i < 32 * 64; i += 512) {
        int r = i >> 6, a = i & 63;
        float v = ((sf[0][r][a] + sf[1][r][a]) + (sf[2][r][a] + sf[3][r][a])) +
                  ((sf[4][r][a] + sf[5][r][a]) + (sf[6][r][a] + sf[7][r][a]));
        __builtin_nontemporal_store(v, &ctx_b[(size_t)r * AD + a]);
    }
}

// ---------------------------------------------------------------------------
extern "C" void kernel_launch(void* const* d_in, const int* in_sizes, int n_in,
                              void* d_out, int out_size, void* d_ws, size_t ws_size,
                              hipStream_t stream) {
    const float* q_in = (const float*)d_in[0];
    const float* k_in = (const float*)d_in[1];
    const float* v_in = (const float*)d_in[2];
    const float* Wq = (const float*)d_in[3];
    const float* bq = (const float*)d_in[4];
    const float* Wk = (const float*)d_in[5];
    const float* bk = (const float*)d_in[6];
    const float* Wv = (const float*)d_in[7];
    const float* bv = (const float*)d_in[8];

    char* ws = (char*)d_ws;
    unsigned short* q_bf = (unsigned short*)(ws);                    // 2 MB
    unsigned short* k_bf = (unsigned short*)(ws + (2u << 20));       // 2 MB
    unsigned short* vT   = (unsigned short*)(ws + (4u << 20));       // 2 MB
    unsigned short* wT   = (unsigned short*)(ws + (6u << 20));       // 384 KB

    float* ctx_out = (float*)d_out;
    float* attn_out = ctx_out + (size_t)NB * SEQ * AD;

    hipLaunchKernelGGL(wT_kernel, dim3(16, 3), dim3(256), 0, stream, Wq, Wk, Wv, wT);
    hipLaunchKernelGGL(proj_kernel, dim3(256, 3), dim3(256), 0, stream,
                       q_in, k_in, v_in, bq, bk, bv, wT, q_bf, k_bf, vT);
    hipLaunchKernelGGL(attn2_kernel, dim3(512), dim3(512), 0, stream,
                       q_bf, k_bf, vT, attn_out, ctx_out);
}